// Round 3
// baseline (358.035 us; speedup 1.0000x reference)
//
#include <hip/hip_runtime.h>
#include <math.h>

#define NROWS 4096
#define EDIM  1024
#define V     50257
#define KNOISE 50
#define KTOT  51
#define NORM_TERM 9.0f
#define NSLOTS 256
#define RPW   13              // rows per wave (f32 fallback)
#define CAP   64              // CSR slots per vocab row (Poisson(4.15); P(>64)~1e-60)
#define ISCALE     16.0f      // input pre-scale: |16x| typ ~16, max ~85 << 448 (e4m3)
#define INV_ISCALE (1.0f / 16.0f)

typedef float floatx2 __attribute__((ext_vector_type(2)));
typedef float floatx4 __attribute__((ext_vector_type(4)));

// ---------------- f32 -> fp8 e4m3 conversion (streaming, generic) ----------
// 16 elems / thread / iter: 4x float4 in, 1x uint4 out (HW v_cvt_pk_fp8_f32).
__global__ __launch_bounds__(256) void convert_f32_fp8(
    const float* __restrict__ src, uint4* __restrict__ dst, int total16, float scale)
{
    int i = blockIdx.x * blockDim.x + threadIdx.x;
    const int stride = gridDim.x * blockDim.x;
    for (; i < total16; i += stride) {
        const float4* p = (const float4*)src + 4 * (size_t)i;
        float4 a0 = p[0], a1 = p[1], a2 = p[2], a3 = p[3];
        uint4 o;
        int d;
        d = 0;
        d = __builtin_amdgcn_cvt_pk_fp8_f32(a0.x * scale, a0.y * scale, d, false);
        d = __builtin_amdgcn_cvt_pk_fp8_f32(a0.z * scale, a0.w * scale, d, true);
        o.x = (unsigned int)d;
        d = 0;
        d = __builtin_amdgcn_cvt_pk_fp8_f32(a1.x * scale, a1.y * scale, d, false);
        d = __builtin_amdgcn_cvt_pk_fp8_f32(a1.z * scale, a1.w * scale, d, true);
        o.y = (unsigned int)d;
        d = 0;
        d = __builtin_amdgcn_cvt_pk_fp8_f32(a2.x * scale, a2.y * scale, d, false);
        d = __builtin_amdgcn_cvt_pk_fp8_f32(a2.z * scale, a2.w * scale, d, true);
        o.z = (unsigned int)d;
        d = 0;
        d = __builtin_amdgcn_cvt_pk_fp8_f32(a3.x * scale, a3.y * scale, d, false);
        d = __builtin_amdgcn_cvt_pk_fp8_f32(a3.z * scale, a3.w * scale, d, true);
        o.w = (unsigned int)d;
        dst[i] = o;
    }
}

// ---------------- bucket the 208,896 (n,k) pairs by vocab row v -------------
// entry = n | 0x80000000 if target pair. cnt[] must be pre-zeroed.
__global__ __launch_bounds__(256) void build_pairs(
    const int* __restrict__ target, const int* __restrict__ noise_samples,
    int* __restrict__ cnt, int* __restrict__ pairs)
{
    const int t = blockIdx.x * 256 + threadIdx.x;
    if (t >= NROWS * KTOT) return;
    const int n = t / KTOT;
    const int k = t - n * KTOT;
    const int v = (k == 0) ? target[n] : noise_samples[n * KNOISE + k - 1];
    const int pos = atomicAdd(&cnt[v], 1);
    if (pos < CAP)
        pairs[(size_t)v * CAP + pos] = (int)((unsigned)n | ((k == 0) ? 0x80000000u : 0u));
}

// ---------------- inverted main kernel: one wave per vocab row v ------------
// Weight: streamed f32 coalesced (read once, nontemporal). Input: fp8 row
// gathers from a 4 MiB table that fits per-XCD L2. All per-v scalars uniform.
__global__ __launch_bounds__(256) void nce_by_v(
    const unsigned char* __restrict__ inq,
    const float* __restrict__ weight,
    const float* __restrict__ bias,
    const float* __restrict__ noise,
    const int*   __restrict__ cnt,
    const int*   __restrict__ pairs,
    float*       __restrict__ partial)
{
    const int wave = threadIdx.x >> 6;
    const int lane = threadIdx.x & 63;
    const int v = blockIdx.x * 4 + wave;
    if (v >= V) return;                    // wave-uniform

    int c = cnt[v];
    if (c == 0) return;                    // wave-uniform; ~1.6% of rows
    if (c > CAP) c = CAP;

    // per-lane preload of CSR entries (c <= 64): lane i holds entry i
    const int eAll = (lane < c) ? pairs[(size_t)v * CAP + lane] : 0;

    // stream this v's weight row (f32, nontemporal): lane covers [16*lane,16*lane+16)
    const floatx4* wrow = (const floatx4*)(weight + (size_t)v * EDIM);
    floatx4 wf[4];
#pragma unroll
    for (int p = 0; p < 4; ++p)
        wf[p] = __builtin_nontemporal_load(wrow + 4 * lane + p);

    const float bz = bias[v];
    const float cz = (float)KNOISE * noise[v];

    float acc = 0.0f;

    // 1-deep software pipeline over pairs
    int e = __shfl(eAll, 0, 64);
    uint4 q = *(const uint4*)(inq + (size_t)(e & 0x7FFFFFFF) * EDIM + 16 * lane);
    for (int i = 0; i < c; ++i) {
        int en = 0;
        uint4 qn = {0, 0, 0, 0};
        if (i + 1 < c) {
            en = __shfl(eAll, i + 1, 64);
            qn = *(const uint4*)(inq + (size_t)(en & 0x7FFFFFFF) * EDIM + 16 * lane);
        }
        const int isT = (int)(((unsigned)e) >> 31);

        float dot = 0.0f;
        const unsigned int wd[4] = { q.x, q.y, q.z, q.w };
#pragma unroll
        for (int d = 0; d < 4; ++d) {
            const floatx2 f0 = __builtin_amdgcn_cvt_pk_f32_fp8((int)wd[d], false);
            const floatx2 f1 = __builtin_amdgcn_cvt_pk_f32_fp8((int)wd[d], true);
            const floatx4 wv = wf[d];
            dot = fmaf(f0.x, wv.x, dot);
            dot = fmaf(f0.y, wv.y, dot);
            dot = fmaf(f1.x, wv.z, dot);
            dot = fmaf(f1.y, wv.w, dot);
        }
#pragma unroll
        for (int off = 32; off > 0; off >>= 1)
            dot += __shfl_xor(dot, off, 64);

        const float pe  = __expf(dot * INV_ISCALE + bz - NORM_TERM);
        const float num = isT ? pe : cz;
        acc += __logf(num / (pe + cz));

        e = en; q = qn;
    }

    if (lane == 0)
        atomicAdd(&partial[v & (NSLOTS - 1)], -acc * (1.0f / (float)NROWS));
}

// ---------------- f32 fallback (R2 structure) if ws too small ---------------
__global__ __launch_bounds__(256) void nce_main_f32(
    const float* __restrict__ input,
    const int*   __restrict__ target,
    const int*   __restrict__ noise_samples,
    const float* __restrict__ noise,
    const float* __restrict__ weight,
    const float* __restrict__ bias,
    float*       __restrict__ partial)
{
    const int n    = blockIdx.x;
    const int tid  = threadIdx.x;
    const int wave = tid >> 6;
    const int lane = tid & 63;

    const float4* inrow = (const float4*)(input + (size_t)n * EDIM);
    float4 inv[4];
#pragma unroll
    for (int p = 0; p < 4; ++p)
        inv[p] = inrow[p * 64 + lane];

    const int start = wave * RPW;
    const int end   = (start + RPW < KTOT) ? start + RPW : KTOT;

    float acc = 0.0f;
    int k = start;
    for (; k + 4 <= end; k += 4) {
        int idx[4];
#pragma unroll
        for (int i = 0; i < 4; ++i) {
            const int kk = k + i;
            idx[i] = (kk == 0) ? target[n] : noise_samples[n * KNOISE + kk - 1];
        }
        float bz[4], cz[4];
#pragma unroll
        for (int i = 0; i < 4; ++i) {
            bz[i] = bias[idx[i]];
            cz[i] = (float)KNOISE * noise[idx[i]];
        }
        float4 wr[4][4];
#pragma unroll
        for (int i = 0; i < 4; ++i) {
            const float4* wrow = (const float4*)(weight + (size_t)idx[i] * EDIM);
#pragma unroll
            for (int p = 0; p < 4; ++p)
                wr[i][p] = wrow[p * 64 + lane];
        }
        float dot[4] = {0.f, 0.f, 0.f, 0.f};
#pragma unroll
        for (int i = 0; i < 4; ++i) {
#pragma unroll
            for (int p = 0; p < 4; ++p) {
                dot[i] = fmaf(inv[p].x, wr[i][p].x, dot[i]);
                dot[i] = fmaf(inv[p].y, wr[i][p].y, dot[i]);
                dot[i] = fmaf(inv[p].z, wr[i][p].z, dot[i]);
                dot[i] = fmaf(inv[p].w, wr[i][p].w, dot[i]);
            }
        }
#pragma unroll
        for (int off = 32; off > 0; off >>= 1) {
#pragma unroll
            for (int i = 0; i < 4; ++i)
                dot[i] += __shfl_xor(dot[i], off, 64);
        }
#pragma unroll
        for (int i = 0; i < 4; ++i) {
            const float p   = __expf(dot[i] + bz[i] - NORM_TERM);
            const float num = (k + i == 0) ? p : cz[i];
            acc += __logf(num / (p + cz[i]));
        }
    }
    for (; k < end; ++k) {
        const int idx = (k == 0) ? target[n] : noise_samples[n * KNOISE + k - 1];
        const float bz = bias[idx];
        const float cz = (float)KNOISE * noise[idx];
        const float4* wrow = (const float4*)(weight + (size_t)idx * EDIM);
        float dot = 0.f;
#pragma unroll
        for (int p = 0; p < 4; ++p) {
            float4 w = wrow[p * 64 + lane];
            dot = fmaf(inv[p].x, w.x, dot);
            dot = fmaf(inv[p].y, w.y, dot);
            dot = fmaf(inv[p].z, w.z, dot);
            dot = fmaf(inv[p].w, w.w, dot);
        }
#pragma unroll
        for (int off = 32; off > 0; off >>= 1)
            dot += __shfl_xor(dot, off, 64);
        const float p   = __expf(dot + bz - NORM_TERM);
        const float num = (k == 0) ? p : cz;
        acc += __logf(num / (p + cz));
    }

    __shared__ float warr[4];
    if (lane == 0) warr[wave] = acc;
    __syncthreads();
    if (tid == 0) {
        const float s = warr[0] + warr[1] + warr[2] + warr[3];
        atomicAdd(&partial[n & (NSLOTS - 1)], -s * (1.0f / (float)NROWS));
    }
}

__global__ __launch_bounds__(64) void nce_finish(const float* __restrict__ partial,
                                                 float* __restrict__ out)
{
    const int lane = threadIdx.x;
    float v = partial[lane] + partial[lane + 64] + partial[lane + 128] + partial[lane + 192];
#pragma unroll
    for (int off = 32; off > 0; off >>= 1)
        v += __shfl_xor(v, off, 64);
    if (lane == 0) out[0] = v;
}

extern "C" void kernel_launch(void* const* d_in, const int* in_sizes, int n_in,
                              void* d_out, int out_size, void* d_ws, size_t ws_size,
                              hipStream_t stream) {
    const float* input         = (const float*)d_in[0];
    const int*   target        = (const int*)  d_in[1];
    const int*   noise_samples = (const int*)  d_in[2];
    const float* noise         = (const float*)d_in[3];
    const float* weight        = (const float*)d_in[4];
    const float* bias          = (const float*)d_in[5];
    float*       out           = (float*)d_out;
    float*       partial       = (float*)d_ws;   // 256 f32 slots at ws[0]

    // workspace layout
    const size_t off_cnt   = 1024;
    const size_t cnt_b     = (size_t)V * sizeof(int);                    // 201,028
    const size_t off_pairs = (off_cnt + cnt_b + 255) & ~(size_t)255;
    const size_t pairs_b   = (size_t)V * CAP * sizeof(int);              // 12,865,792
    const size_t off_inq   = (off_pairs + pairs_b + 255) & ~(size_t)255;
    const size_t inq_b     = (size_t)NROWS * EDIM;                       // 4,194,304
    const size_t need      = off_inq + inq_b;                            // ~17.3 MB

    (void)hipMemsetAsync(partial, 0, NSLOTS * sizeof(float), stream);

    if (ws_size >= need) {
        int*           cnt   = (int*)((char*)d_ws + off_cnt);
        int*           pairs = (int*)((char*)d_ws + off_pairs);
        unsigned char* inq   = (unsigned char*)d_ws + off_inq;

        (void)hipMemsetAsync(cnt, 0, cnt_b, stream);
        // quantize input rows to fp8 (4 MiB table -> fits per-XCD L2)
        convert_f32_fp8<<<1024, 256, 0, stream>>>(
            input, (uint4*)inq, NROWS * EDIM / 16, ISCALE);
        // bucket pairs by vocab row
        build_pairs<<<(NROWS * KTOT + 255) / 256, 256, 0, stream>>>(
            target, noise_samples, cnt, pairs);
        // inverted main: stream weight once, gather hot fp8 input rows
        nce_by_v<<<(V + 3) / 4, 256, 0, stream>>>(
            inq, weight, bias, noise, cnt, pairs, partial);
    } else {
        nce_main_f32<<<NROWS, 256, 0, stream>>>(
            input, target, noise_samples, noise, weight, bias, partial);
    }
    nce_finish<<<1, 64, 0, stream>>>(partial, out);
}

// Round 4
// 355.296 us; speedup vs baseline: 1.0077x; 1.0077x over previous
//
#include <hip/hip_runtime.h>
#include <math.h>

#define NROWS 4096
#define EDIM  1024
#define V     50257
#define KNOISE 50
#define KTOT  51
#define NORM_TERM 9.0f
#define NSLOTS 256
#define RPW   13              // rows per wave (f32 fallback)
#define CAP   64              // CSR slots per vocab row (Poisson(4.15); P(>64)~1e-60)
#define ISCALE     16.0f      // input pre-scale: |16x| typ ~16, max ~85 << 448 (e4m3)
#define INV_ISCALE (1.0f / 16.0f)

typedef float floatx2 __attribute__((ext_vector_type(2)));
typedef float floatx4 __attribute__((ext_vector_type(4)));

// ---------------- prep: zero bookkeeping + f32 -> fp8 input table ----------
// Grid exactly 1024x256: thread gid converts input[16*gid .. 16*gid+15] and
// the low threads also zero cnt[] (50257 ints) and partial[] (256 floats).
__global__ __launch_bounds__(256) void prep(
    const float* __restrict__ input, uint4* __restrict__ inq_v,
    int* __restrict__ cnt, float* __restrict__ partial)
{
    const int gid = blockIdx.x * 256 + threadIdx.x;   // 0 .. 262143
    if (gid < NSLOTS) partial[gid] = 0.0f;
    if (gid < V)      cnt[gid] = 0;

    const float4* p = (const float4*)input + 4 * (size_t)gid;
    float4 a0 = p[0], a1 = p[1], a2 = p[2], a3 = p[3];
    uint4 o;
    int d;
    d = 0;
    d = __builtin_amdgcn_cvt_pk_fp8_f32(a0.x * ISCALE, a0.y * ISCALE, d, false);
    d = __builtin_amdgcn_cvt_pk_fp8_f32(a0.z * ISCALE, a0.w * ISCALE, d, true);
    o.x = (unsigned int)d;
    d = 0;
    d = __builtin_amdgcn_cvt_pk_fp8_f32(a1.x * ISCALE, a1.y * ISCALE, d, false);
    d = __builtin_amdgcn_cvt_pk_fp8_f32(a1.z * ISCALE, a1.w * ISCALE, d, true);
    o.y = (unsigned int)d;
    d = 0;
    d = __builtin_amdgcn_cvt_pk_fp8_f32(a2.x * ISCALE, a2.y * ISCALE, d, false);
    d = __builtin_amdgcn_cvt_pk_fp8_f32(a2.z * ISCALE, a2.w * ISCALE, d, true);
    o.z = (unsigned int)d;
    d = 0;
    d = __builtin_amdgcn_cvt_pk_fp8_f32(a3.x * ISCALE, a3.y * ISCALE, d, false);
    d = __builtin_amdgcn_cvt_pk_fp8_f32(a3.z * ISCALE, a3.w * ISCALE, d, true);
    o.w = (unsigned int)d;
    inq_v[gid] = o;
}

// ---------------- bucket the 208,896 (n,k) pairs by vocab row v -------------
// entry = n | 0x80000000 if target pair. cnt[] zeroed by prep.
__global__ __launch_bounds__(256) void build_pairs(
    const int* __restrict__ target, const int* __restrict__ noise_samples,
    int* __restrict__ cnt, int* __restrict__ pairs)
{
    const int t = blockIdx.x * 256 + threadIdx.x;
    if (t >= NROWS * KTOT) return;
    const int n = t / KTOT;
    const int k = t - n * KTOT;
    const int v = (k == 0) ? target[n] : noise_samples[n * KNOISE + k - 1];
    const int pos = atomicAdd(&cnt[v], 1);
    if (pos < CAP)
        pairs[(size_t)v * CAP + pos] = (int)((unsigned)n | ((k == 0) ? 0x80000000u : 0u));
}

// ---------------- inverted main kernel: one wave per vocab row v ------------
// Weight: streamed f32 coalesced (read once, nontemporal), loads issued FIRST
// so the HBM stream stays in flight under the cnt->pairs dependency chain.
// Input: fp8 row gathers from a 4 MiB table that fits per-XCD L2.
__global__ __launch_bounds__(256) void nce_by_v(
    const unsigned char* __restrict__ inq,
    const float* __restrict__ weight,
    const float* __restrict__ bias,
    const float* __restrict__ noise,
    const int*   __restrict__ cnt,
    const int*   __restrict__ pairs,
    float*       __restrict__ partial)
{
    const int wave = threadIdx.x >> 6;
    const int lane = threadIdx.x & 63;
    const int v = blockIdx.x * 4 + wave;
    if (v >= V) return;                    // wave-uniform (3 excess waves)

    // issue the HBM weight-row loads immediately (the long-latency item)
    const floatx4* wrow = (const floatx4*)(weight + (size_t)v * EDIM);
    floatx4 wf[4];
#pragma unroll
    for (int p = 0; p < 4; ++p)
        wf[p] = __builtin_nontemporal_load(wrow + 4 * lane + p);

    int c = cnt[v];
    if (c > CAP) c = CAP;

    // per-lane preload of CSR entries (c <= 64): lane i holds entry i
    const int eAll = (lane < c) ? pairs[(size_t)v * CAP + lane] : 0;

    const float bz = bias[v];
    const float cz = (float)KNOISE * noise[v];

    float acc = 0.0f;

    // 1-deep software pipeline over pairs (zero-trip if c == 0; ~1.6% of rows)
    int e = __shfl(eAll, 0, 64);
    uint4 q = {0, 0, 0, 0};
    if (c > 0)
        q = *(const uint4*)(inq + (size_t)(e & 0x7FFFFFFF) * EDIM + 16 * lane);
    for (int i = 0; i < c; ++i) {
        int en = 0;
        uint4 qn = {0, 0, 0, 0};
        if (i + 1 < c) {
            en = __shfl(eAll, i + 1, 64);
            qn = *(const uint4*)(inq + (size_t)(en & 0x7FFFFFFF) * EDIM + 16 * lane);
        }
        const int isT = (int)(((unsigned)e) >> 31);

        float dot = 0.0f;
        const unsigned int wd[4] = { q.x, q.y, q.z, q.w };
#pragma unroll
        for (int d = 0; d < 4; ++d) {
            const floatx2 f0 = __builtin_amdgcn_cvt_pk_f32_fp8((int)wd[d], false);
            const floatx2 f1 = __builtin_amdgcn_cvt_pk_f32_fp8((int)wd[d], true);
            const floatx4 wv = wf[d];
            dot = fmaf(f0.x, wv.x, dot);
            dot = fmaf(f0.y, wv.y, dot);
            dot = fmaf(f1.x, wv.z, dot);
            dot = fmaf(f1.y, wv.w, dot);
        }
#pragma unroll
        for (int off = 32; off > 0; off >>= 1)
            dot += __shfl_xor(dot, off, 64);

        const float pe  = __expf(dot * INV_ISCALE + bz - NORM_TERM);
        const float num = isT ? pe : cz;
        acc += __logf(num / (pe + cz));

        e = en; q = qn;
    }

    if (lane == 0 && c > 0)
        atomicAdd(&partial[v & (NSLOTS - 1)], -acc * (1.0f / (float)NROWS));
}

// ---------------- f32 fallback (R2 structure) if ws too small ---------------
__global__ __launch_bounds__(256) void nce_main_f32(
    const float* __restrict__ input,
    const int*   __restrict__ target,
    const int*   __restrict__ noise_samples,
    const float* __restrict__ noise,
    const float* __restrict__ weight,
    const float* __restrict__ bias,
    float*       __restrict__ partial)
{
    const int n    = blockIdx.x;
    const int tid  = threadIdx.x;
    const int wave = tid >> 6;
    const int lane = tid & 63;

    const float4* inrow = (const float4*)(input + (size_t)n * EDIM);
    float4 inv[4];
#pragma unroll
    for (int p = 0; p < 4; ++p)
        inv[p] = inrow[p * 64 + lane];

    const int start = wave * RPW;
    const int end   = (start + RPW < KTOT) ? start + RPW : KTOT;

    float acc = 0.0f;
    int k = start;
    for (; k + 4 <= end; k += 4) {
        int idx[4];
#pragma unroll
        for (int i = 0; i < 4; ++i) {
            const int kk = k + i;
            idx[i] = (kk == 0) ? target[n] : noise_samples[n * KNOISE + kk - 1];
        }
        float bz[4], cz[4];
#pragma unroll
        for (int i = 0; i < 4; ++i) {
            bz[i] = bias[idx[i]];
            cz[i] = (float)KNOISE * noise[idx[i]];
        }
        float4 wr[4][4];
#pragma unroll
        for (int i = 0; i < 4; ++i) {
            const float4* wrow = (const float4*)(weight + (size_t)idx[i] * EDIM);
#pragma unroll
            for (int p = 0; p < 4; ++p)
                wr[i][p] = wrow[p * 64 + lane];
        }
        float dot[4] = {0.f, 0.f, 0.f, 0.f};
#pragma unroll
        for (int i = 0; i < 4; ++i) {
#pragma unroll
            for (int p = 0; p < 4; ++p) {
                dot[i] = fmaf(inv[p].x, wr[i][p].x, dot[i]);
                dot[i] = fmaf(inv[p].y, wr[i][p].y, dot[i]);
                dot[i] = fmaf(inv[p].z, wr[i][p].z, dot[i]);
                dot[i] = fmaf(inv[p].w, wr[i][p].w, dot[i]);
            }
        }
#pragma unroll
        for (int off = 32; off > 0; off >>= 1) {
#pragma unroll
            for (int i = 0; i < 4; ++i)
                dot[i] += __shfl_xor(dot[i], off, 64);
        }
#pragma unroll
        for (int i = 0; i < 4; ++i) {
            const float p   = __expf(dot[i] + bz[i] - NORM_TERM);
            const float num = (k + i == 0) ? p : cz[i];
            acc += __logf(num / (p + cz[i]));
        }
    }
    for (; k < end; ++k) {
        const int idx = (k == 0) ? target[n] : noise_samples[n * KNOISE + k - 1];
        const float bz = bias[idx];
        const float cz = (float)KNOISE * noise[idx];
        const float4* wrow = (const float4*)(weight + (size_t)idx * EDIM);
        float dot = 0.f;
#pragma unroll
        for (int p = 0; p < 4; ++p) {
            float4 w = wrow[p * 64 + lane];
            dot = fmaf(inv[p].x, w.x, dot);
            dot = fmaf(inv[p].y, w.y, dot);
            dot = fmaf(inv[p].z, w.z, dot);
            dot = fmaf(inv[p].w, w.w, dot);
        }
#pragma unroll
        for (int off = 32; off > 0; off >>= 1)
            dot += __shfl_xor(dot, off, 64);
        const float p   = __expf(dot + bz - NORM_TERM);
        const float num = (k == 0) ? p : cz;
        acc += __logf(num / (p + cz));
    }

    __shared__ float warr[4];
    if (lane == 0) warr[wave] = acc;
    __syncthreads();
    if (tid == 0) {
        const float s = warr[0] + warr[1] + warr[2] + warr[3];
        atomicAdd(&partial[n & (NSLOTS - 1)], -s * (1.0f / (float)NROWS));
    }
}

__global__ __launch_bounds__(64) void nce_finish(const float* __restrict__ partial,
                                                 float* __restrict__ out)
{
    const int lane = threadIdx.x;
    float v = partial[lane] + partial[lane + 64] + partial[lane + 128] + partial[lane + 192];
#pragma unroll
    for (int off = 32; off > 0; off >>= 1)
        v += __shfl_xor(v, off, 64);
    if (lane == 0) out[0] = v;
}

extern "C" void kernel_launch(void* const* d_in, const int* in_sizes, int n_in,
                              void* d_out, int out_size, void* d_ws, size_t ws_size,
                              hipStream_t stream) {
    const float* input         = (const float*)d_in[0];
    const int*   target        = (const int*)  d_in[1];
    const int*   noise_samples = (const int*)  d_in[2];
    const float* noise         = (const float*)d_in[3];
    const float* weight        = (const float*)d_in[4];
    const float* bias          = (const float*)d_in[5];
    float*       out           = (float*)d_out;
    float*       partial       = (float*)d_ws;   // 256 f32 slots at ws[0]

    // workspace layout
    const size_t off_cnt   = 1024;
    const size_t cnt_b     = (size_t)V * sizeof(int);                    // 201,028
    const size_t off_pairs = (off_cnt + cnt_b + 255) & ~(size_t)255;
    const size_t pairs_b   = (size_t)V * CAP * sizeof(int);              // 12,865,792
    const size_t off_inq   = (off_pairs + pairs_b + 255) & ~(size_t)255;
    const size_t inq_b     = (size_t)NROWS * EDIM;                       // 4,194,304
    const size_t need      = off_inq + inq_b;                            // ~17.3 MB

    if (ws_size >= need) {
        int*           cnt   = (int*)((char*)d_ws + off_cnt);
        int*           pairs = (int*)((char*)d_ws + off_pairs);
        unsigned char* inq   = (unsigned char*)d_ws + off_inq;

        // prep: zero partial+cnt, quantize input rows to fp8 (4 MiB table)
        prep<<<NROWS * EDIM / 16 / 256, 256, 0, stream>>>(
            input, (uint4*)inq, cnt, partial);
        // bucket pairs by vocab row
        build_pairs<<<(NROWS * KTOT + 255) / 256, 256, 0, stream>>>(
            target, noise_samples, cnt, pairs);
        // inverted main: stream weight once, gather hot fp8 input rows
        nce_by_v<<<(V + 3) / 4, 256, 0, stream>>>(
            inq, weight, bias, noise, cnt, pairs, partial);
    } else {
        (void)hipMemsetAsync(partial, 0, NSLOTS * sizeof(float), stream);
        nce_main_f32<<<NROWS, 256, 0, stream>>>(
            input, target, noise_samples, noise, weight, bias, partial);
    }
    nce_finish<<<1, 64, 0, stream>>>(partial, out);
}

// Round 5
// 352.196 us; speedup vs baseline: 1.0166x; 1.0088x over previous
//
#include <hip/hip_runtime.h>
#include <math.h>

#define NROWS 4096
#define EDIM  1024
#define V     50257
#define KNOISE 50
#define KTOT  51
#define NORM_TERM 9.0f
#define NSLOTS 256
#define RPW   13              // rows per wave (f32 fallback)
#define CAP   64              // CSR slots per vocab row (Poisson(4.15); P(>64)~1e-60)
#define ISCALE     16.0f      // input pre-scale: |16x| typ ~16, max ~85 << 448 (e4m3)
#define INV_ISCALE (1.0f / 16.0f)

typedef float floatx2 __attribute__((ext_vector_type(2)));
typedef float floatx4 __attribute__((ext_vector_type(4)));

// ---------------- prep: zero bookkeeping + f32 -> fp8 input table ----------
// Grid exactly 1024x256: thread gid converts input[16*gid .. 16*gid+15] and
// the low threads also zero cnt[] (50257 ints) and partial[] (256 floats).
__global__ __launch_bounds__(256) void prep(
    const float* __restrict__ input, uint4* __restrict__ inq_v,
    int* __restrict__ cnt, float* __restrict__ partial)
{
    const int gid = blockIdx.x * 256 + threadIdx.x;   // 0 .. 262143
    if (gid < NSLOTS) partial[gid] = 0.0f;
    if (gid < V)      cnt[gid] = 0;

    const float4* p = (const float4*)input + 4 * (size_t)gid;
    float4 a0 = p[0], a1 = p[1], a2 = p[2], a3 = p[3];
    uint4 o;
    int d;
    d = 0;
    d = __builtin_amdgcn_cvt_pk_fp8_f32(a0.x * ISCALE, a0.y * ISCALE, d, false);
    d = __builtin_amdgcn_cvt_pk_fp8_f32(a0.z * ISCALE, a0.w * ISCALE, d, true);
    o.x = (unsigned int)d;
    d = 0;
    d = __builtin_amdgcn_cvt_pk_fp8_f32(a1.x * ISCALE, a1.y * ISCALE, d, false);
    d = __builtin_amdgcn_cvt_pk_fp8_f32(a1.z * ISCALE, a1.w * ISCALE, d, true);
    o.y = (unsigned int)d;
    d = 0;
    d = __builtin_amdgcn_cvt_pk_fp8_f32(a2.x * ISCALE, a2.y * ISCALE, d, false);
    d = __builtin_amdgcn_cvt_pk_fp8_f32(a2.z * ISCALE, a2.w * ISCALE, d, true);
    o.z = (unsigned int)d;
    d = 0;
    d = __builtin_amdgcn_cvt_pk_fp8_f32(a3.x * ISCALE, a3.y * ISCALE, d, false);
    d = __builtin_amdgcn_cvt_pk_fp8_f32(a3.z * ISCALE, a3.w * ISCALE, d, true);
    o.w = (unsigned int)d;
    inq_v[gid] = o;
}

// ---------------- bucket the 208,896 (n,k) pairs by vocab row v -------------
// entry = n | 0x80000000 if target pair. cnt[] zeroed by prep.
__global__ __launch_bounds__(256) void build_pairs(
    const int* __restrict__ target, const int* __restrict__ noise_samples,
    int* __restrict__ cnt, int* __restrict__ pairs)
{
    const int t = blockIdx.x * 256 + threadIdx.x;
    if (t >= NROWS * KTOT) return;
    const int n = t / KTOT;
    const int k = t - n * KTOT;
    const int v = (k == 0) ? target[n] : noise_samples[n * KNOISE + k - 1];
    const int pos = atomicAdd(&cnt[v], 1);
    if (pos < CAP)
        pairs[(size_t)v * CAP + pos] = (int)((unsigned)n | ((k == 0) ? 0x80000000u : 0u));
}

// ---------------- inverted main kernel: one wave per vocab row v ------------
// Weight: streamed f32, CONTIGUOUS 1KB per load instruction (lane l, load p
// covers bytes [1024p + 16l)) -> 16 cache lines/instr, peak stream rate.
// Input: fp8 dword gathers (bytes [256p + 4l), 256B contiguous/instr) from a
// 4 MiB table that fits per-XCD L2. Lane l holds elems {256p+4l..+3} of BOTH
// operands; element->lane assignment is arbitrary thanks to the butterfly.
__global__ __launch_bounds__(256) void nce_by_v(
    const unsigned char* __restrict__ inq,
    const float* __restrict__ weight,
    const float* __restrict__ bias,
    const float* __restrict__ noise,
    const int*   __restrict__ cnt,
    const int*   __restrict__ pairs,
    float*       __restrict__ partial)
{
    const int wave = threadIdx.x >> 6;
    const int lane = threadIdx.x & 63;
    const int v = blockIdx.x * 4 + wave;
    if (v >= V) return;                    // wave-uniform (3 excess waves)

    // issue the HBM weight-row loads immediately (the long-latency item)
    const floatx4* wrow = (const floatx4*)(weight + (size_t)v * EDIM);
    floatx4 wf[4];
#pragma unroll
    for (int p = 0; p < 4; ++p)
        wf[p] = __builtin_nontemporal_load(wrow + 64 * p + lane);  // 1KB contig

    int c = cnt[v];
    if (c > CAP) c = CAP;

    // per-lane preload of CSR entries (c <= 64): lane i holds entry i
    const int eAll = (lane < c) ? pairs[(size_t)v * CAP + lane] : 0;

    const float bz = bias[v];
    const float cz = (float)KNOISE * noise[v];

    float acc = 0.0f;

    // 1-deep software pipeline over pairs (zero-trip if c == 0; ~1.6% of rows)
    int e = __shfl(eAll, 0, 64);
    unsigned int q[4] = {0, 0, 0, 0};
    if (c > 0) {
        const unsigned int* qrow =
            (const unsigned int*)(inq + (size_t)(e & 0x7FFFFFFF) * EDIM);
#pragma unroll
        for (int p = 0; p < 4; ++p)
            q[p] = qrow[64 * p + lane];                 // 256B contig per instr
    }
    for (int i = 0; i < c; ++i) {
        int en = 0;
        unsigned int qn[4] = {0, 0, 0, 0};
        if (i + 1 < c) {
            en = __shfl(eAll, i + 1, 64);
            const unsigned int* qrow =
                (const unsigned int*)(inq + (size_t)(en & 0x7FFFFFFF) * EDIM);
#pragma unroll
            for (int p = 0; p < 4; ++p)
                qn[p] = qrow[64 * p + lane];
        }
        const int isT = (int)(((unsigned)e) >> 31);

        float dot = 0.0f;
#pragma unroll
        for (int p = 0; p < 4; ++p) {
            const floatx2 f0 = __builtin_amdgcn_cvt_pk_f32_fp8((int)q[p], false);
            const floatx2 f1 = __builtin_amdgcn_cvt_pk_f32_fp8((int)q[p], true);
            const floatx4 wv = wf[p];
            dot = fmaf(f0.x, wv.x, dot);
            dot = fmaf(f0.y, wv.y, dot);
            dot = fmaf(f1.x, wv.z, dot);
            dot = fmaf(f1.y, wv.w, dot);
        }
#pragma unroll
        for (int off = 32; off > 0; off >>= 1)
            dot += __shfl_xor(dot, off, 64);

        const float pe  = __expf(dot * INV_ISCALE + bz - NORM_TERM);
        const float num = isT ? pe : cz;
        acc += __logf(num / (pe + cz));

        e = en;
#pragma unroll
        for (int p = 0; p < 4; ++p) q[p] = qn[p];
    }

    if (lane == 0 && c > 0)
        atomicAdd(&partial[v & (NSLOTS - 1)], -acc * (1.0f / (float)NROWS));
}

// ---------------- f32 fallback (R2 structure) if ws too small ---------------
__global__ __launch_bounds__(256) void nce_main_f32(
    const float* __restrict__ input,
    const int*   __restrict__ target,
    const int*   __restrict__ noise_samples,
    const float* __restrict__ noise,
    const float* __restrict__ weight,
    const float* __restrict__ bias,
    float*       __restrict__ partial)
{
    const int n    = blockIdx.x;
    const int tid  = threadIdx.x;
    const int wave = tid >> 6;
    const int lane = tid & 63;

    const float4* inrow = (const float4*)(input + (size_t)n * EDIM);
    float4 inv[4];
#pragma unroll
    for (int p = 0; p < 4; ++p)
        inv[p] = inrow[p * 64 + lane];

    const int start = wave * RPW;
    const int end   = (start + RPW < KTOT) ? start + RPW : KTOT;

    float acc = 0.0f;
    int k = start;
    for (; k + 4 <= end; k += 4) {
        int idx[4];
#pragma unroll
        for (int i = 0; i < 4; ++i) {
            const int kk = k + i;
            idx[i] = (kk == 0) ? target[n] : noise_samples[n * KNOISE + kk - 1];
        }
        float bz[4], cz[4];
#pragma unroll
        for (int i = 0; i < 4; ++i) {
            bz[i] = bias[idx[i]];
            cz[i] = (float)KNOISE * noise[idx[i]];
        }
        float4 wr[4][4];
#pragma unroll
        for (int i = 0; i < 4; ++i) {
            const float4* wrow = (const float4*)(weight + (size_t)idx[i] * EDIM);
#pragma unroll
            for (int p = 0; p < 4; ++p)
                wr[i][p] = wrow[p * 64 + lane];
        }
        float dot[4] = {0.f, 0.f, 0.f, 0.f};
#pragma unroll
        for (int i = 0; i < 4; ++i) {
#pragma unroll
            for (int p = 0; p < 4; ++p) {
                dot[i] = fmaf(inv[p].x, wr[i][p].x, dot[i]);
                dot[i] = fmaf(inv[p].y, wr[i][p].y, dot[i]);
                dot[i] = fmaf(inv[p].z, wr[i][p].z, dot[i]);
                dot[i] = fmaf(inv[p].w, wr[i][p].w, dot[i]);
            }
        }
#pragma unroll
        for (int off = 32; off > 0; off >>= 1) {
#pragma unroll
            for (int i = 0; i < 4; ++i)
                dot[i] += __shfl_xor(dot[i], off, 64);
        }
#pragma unroll
        for (int i = 0; i < 4; ++i) {
            const float p   = __expf(dot[i] + bz[i] - NORM_TERM);
            const float num = (k + i == 0) ? p : cz[i];
            acc += __logf(num / (p + cz[i]));
        }
    }
    for (; k < end; ++k) {
        const int idx = (k == 0) ? target[n] : noise_samples[n * KNOISE + k - 1];
        const float bz = bias[idx];
        const float cz = (float)KNOISE * noise[idx];
        const float4* wrow = (const float4*)(weight + (size_t)idx * EDIM);
        float dot = 0.f;
#pragma unroll
        for (int p = 0; p < 4; ++p) {
            float4 w = wrow[p * 64 + lane];
            dot = fmaf(inv[p].x, w.x, dot);
            dot = fmaf(inv[p].y, w.y, dot);
            dot = fmaf(inv[p].z, w.z, dot);
            dot = fmaf(inv[p].w, w.w, dot);
        }
#pragma unroll
        for (int off = 32; off > 0; off >>= 1)
            dot += __shfl_xor(dot, off, 64);
        const float p   = __expf(dot + bz - NORM_TERM);
        const float num = (k == 0) ? p : cz;
        acc += __logf(num / (p + cz));
    }

    __shared__ float warr[4];
    if (lane == 0) warr[wave] = acc;
    __syncthreads();
    if (tid == 0) {
        const float s = warr[0] + warr[1] + warr[2] + warr[3];
        atomicAdd(&partial[n & (NSLOTS - 1)], -s * (1.0f / (float)NROWS));
    }
}

__global__ __launch_bounds__(64) void nce_finish(const float* __restrict__ partial,
                                                 float* __restrict__ out)
{
    const int lane = threadIdx.x;
    float v = partial[lane] + partial[lane + 64] + partial[lane + 128] + partial[lane + 192];
#pragma unroll
    for (int off = 32; off > 0; off >>= 1)
        v += __shfl_xor(v, off, 64);
    if (lane == 0) out[0] = v;
}

extern "C" void kernel_launch(void* const* d_in, const int* in_sizes, int n_in,
                              void* d_out, int out_size, void* d_ws, size_t ws_size,
                              hipStream_t stream) {
    const float* input         = (const float*)d_in[0];
    const int*   target        = (const int*)  d_in[1];
    const int*   noise_samples = (const int*)  d_in[2];
    const float* noise         = (const float*)d_in[3];
    const float* weight        = (const float*)d_in[4];
    const float* bias          = (const float*)d_in[5];
    float*       out           = (float*)d_out;
    float*       partial       = (float*)d_ws;   // 256 f32 slots at ws[0]

    // workspace layout
    const size_t off_cnt   = 1024;
    const size_t cnt_b     = (size_t)V * sizeof(int);                    // 201,028
    const size_t off_pairs = (off_cnt + cnt_b + 255) & ~(size_t)255;
    const size_t pairs_b   = (size_t)V * CAP * sizeof(int);              // 12,865,792
    const size_t off_inq   = (off_pairs + pairs_b + 255) & ~(size_t)255;
    const size_t inq_b     = (size_t)NROWS * EDIM;                       // 4,194,304
    const size_t need      = off_inq + inq_b;                            // ~17.3 MB

    if (ws_size >= need) {
        int*           cnt   = (int*)((char*)d_ws + off_cnt);
        int*           pairs = (int*)((char*)d_ws + off_pairs);
        unsigned char* inq   = (unsigned char*)d_ws + off_inq;

        // prep: zero partial+cnt, quantize input rows to fp8 (4 MiB table)
        prep<<<NROWS * EDIM / 16 / 256, 256, 0, stream>>>(
            input, (uint4*)inq, cnt, partial);
        // bucket pairs by vocab row
        build_pairs<<<(NROWS * KTOT + 255) / 256, 256, 0, stream>>>(
            target, noise_samples, cnt, pairs);
        // inverted main: stream weight once, gather hot fp8 input rows
        nce_by_v<<<(V + 3) / 4, 256, 0, stream>>>(
            inq, weight, bias, noise, cnt, pairs, partial);
    } else {
        (void)hipMemsetAsync(partial, 0, NSLOTS * sizeof(float), stream);
        nce_main_f32<<<NROWS, 256, 0, stream>>>(
            input, target, noise_samples, noise, weight, bias, partial);
    }
    nce_finish<<<1, 64, 0, stream>>>(partial, out);
}